// Round 1
// baseline (1121.944 us; speedup 1.0000x reference)
//
#include <hip/hip_runtime.h>
#include <hip/hip_bf16.h>
#include <math.h>

#define B_SZ 32
#define VLEN_SZ 2048
#define H_SZ 1024
#define DIM_SZ 1024
#define C_SZ 32

typedef float f32x4 __attribute__((ext_vector_type(4)));
typedef short s16x8 __attribute__((ext_vector_type(8)));
typedef short s16x4 __attribute__((ext_vector_type(4)));

__device__ __forceinline__ short f2bf(float f) {
  unsigned u = __float_as_uint(f);
  u = (u + 0x7fffu + ((u >> 16) & 1u)) >> 16;  // RNE
  return (short)u;
}

__device__ __forceinline__ float fast_tanh(float x) {
  float z = __expf(2.0f * x);
  return 1.0f - 2.0f / (z + 1.0f);
}

// ---- qp[b,d] = dot(query[b,:], w_q[d,:]) + bias[d]; one wave per output ----
__global__ void k_qpb(const float* __restrict__ query, const float* __restrict__ w_q,
                      const float* __restrict__ bias, float* __restrict__ qpb) {
  int wid = blockIdx.x * 4 + (threadIdx.x >> 6);
  int lane = threadIdx.x & 63;
  int d = wid >> 5;
  int b = wid & 31;
  const f32x4* q4 = (const f32x4*)(query + (size_t)b * H_SZ);
  const f32x4* w4 = (const f32x4*)(w_q + (size_t)d * H_SZ);
  float acc = 0.f;
#pragma unroll
  for (int it = 0; it < 4; ++it) {
    int k = it * 64 + lane;
    f32x4 a = q4[k], w = w4[k];
    acc += a[0] * w[0] + a[1] * w[1] + a[2] * w[2] + a[3] * w[3];
  }
#pragma unroll
  for (int off = 32; off; off >>= 1) acc += __shfl_xor(acc, off, 64);
  if (lane == 0) qpb[(size_t)b * DIM_SZ + d] = acc + bias[d];
}

// ---- fp32 -> bf16 cast (n4 = number of float4 groups) ----
__global__ void k_f2bf(const float* __restrict__ src, short* __restrict__ dst, int n4) {
  int i = blockIdx.x * blockDim.x + threadIdx.x;
  if (i >= n4) return;
  f32x4 v = ((const f32x4*)src)[i];
  s16x4 o;
  o[0] = f2bf(v[0]); o[1] = f2bf(v[1]); o[2] = f2bf(v[2]); o[3] = f2bf(v[3]);
  ((s16x4*)dst)[i] = o;
}

// ---- conv features cf[b,v,c] (bf16), k=3 pad=1 conv over prev_attn ----
__global__ void k_cf(const float* __restrict__ prev, const float* __restrict__ conv_w,
                     const float* __restrict__ conv_b, short* __restrict__ cfb) {
  int t = blockIdx.x * 256 + threadIdx.x;  // row index b*VLEN+v
  int v = t & (VLEN_SZ - 1);
  float p0 = prev[t];
  float pm = (v > 0) ? prev[t - 1] : 0.f;
  float pp = (v < VLEN_SZ - 1) ? prev[t + 1] : 0.f;
#pragma unroll
  for (int c = 0; c < C_SZ; ++c) {
    float f = conv_b[c] + pm * conv_w[c * 3 + 0] + p0 * conv_w[c * 3 + 1] + pp * conv_w[c * 3 + 2];
    cfb[(size_t)t * C_SZ + c] = f2bf(f);
  }
}

// ---- main fused kernel: vp GEMM (bf16 MFMA) + lp K-step + tanh + score dot ----
// block: 4 waves; 64 rows x 256 d. grid (1024, 4).
__global__ __launch_bounds__(256, 2) void k_score(
    const float* __restrict__ value, const short* __restrict__ wvb,
    const short* __restrict__ wlocb, const short* __restrict__ cfb,
    const float* __restrict__ qpb, const float* __restrict__ w_score,
    float* __restrict__ score) {
  int wave = threadIdx.x >> 6;
  int lane = threadIdx.x & 63;
  int quad = lane >> 4;
  int l16 = lane & 15;
  int r0 = blockIdx.x * 64;                    // global row base (b*VLEN+v)
  int b = r0 >> 11;                            // VLEN = 2048
  int d0 = blockIdx.y * 256 + wave * 64;

  f32x4 acc[4][4];
#pragma unroll
  for (int i = 0; i < 4; ++i)
#pragma unroll
    for (int j = 0; j < 4; ++j) acc[i][j] = (f32x4){0.f, 0.f, 0.f, 0.f};

  s16x8 a[4], bb[4];

  for (int h0 = 0; h0 < H_SZ; h0 += 32) {
#pragma unroll
    for (int i = 0; i < 4; ++i) {
      const float* ap = value + (size_t)(r0 + i * 16 + l16) * H_SZ + h0 + quad * 8;
      f32x4 x0 = *(const f32x4*)ap;
      f32x4 x1 = *(const f32x4*)(ap + 4);
      s16x8 af;
      af[0] = f2bf(x0[0]); af[1] = f2bf(x0[1]); af[2] = f2bf(x0[2]); af[3] = f2bf(x0[3]);
      af[4] = f2bf(x1[0]); af[5] = f2bf(x1[1]); af[6] = f2bf(x1[2]); af[7] = f2bf(x1[3]);
      a[i] = af;
    }
#pragma unroll
    for (int j = 0; j < 4; ++j)
      bb[j] = *(const s16x8*)(wvb + (size_t)(d0 + j * 16 + l16) * H_SZ + h0 + quad * 8);
#pragma unroll
    for (int i = 0; i < 4; ++i)
#pragma unroll
      for (int j = 0; j < 4; ++j)
        acc[i][j] = __builtin_amdgcn_mfma_f32_16x16x32_bf16(a[i], bb[j], acc[i][j], 0, 0, 0);
  }

  // location-feature K-step: A = cf (K=32), B = w_loc
  {
#pragma unroll
    for (int i = 0; i < 4; ++i)
      a[i] = *(const s16x8*)(cfb + (size_t)(r0 + i * 16 + l16) * C_SZ + quad * 8);
#pragma unroll
    for (int j = 0; j < 4; ++j)
      bb[j] = *(const s16x8*)(wlocb + (size_t)(d0 + j * 16 + l16) * C_SZ + quad * 8);
#pragma unroll
    for (int i = 0; i < 4; ++i)
#pragma unroll
      for (int j = 0; j < 4; ++j)
        acc[i][j] = __builtin_amdgcn_mfma_f32_16x16x32_bf16(a[i], bb[j], acc[i][j], 0, 0, 0);
  }

  // epilogue: e = tanh(acc + qp + bias), partial score = sum_d e * w_score[d]
  float qv[4], wv[4];
#pragma unroll
  for (int j = 0; j < 4; ++j) {
    int d = d0 + j * 16 + l16;
    qv[j] = qpb[(size_t)b * DIM_SZ + d];
    wv[j] = w_score[d];
  }

  __shared__ float sred[4][64];
#pragma unroll
  for (int i = 0; i < 4; ++i) {
#pragma unroll
    for (int r = 0; r < 4; ++r) {
      float part = 0.f;
#pragma unroll
      for (int j = 0; j < 4; ++j) {
        float e = fast_tanh(acc[i][j][r] + qv[j]);
        part += e * wv[j];
      }
      part += __shfl_xor(part, 1);
      part += __shfl_xor(part, 2);
      part += __shfl_xor(part, 4);
      part += __shfl_xor(part, 8);
      if (l16 == 0) sred[wave][i * 16 + quad * 4 + r] = part;
    }
  }
  __syncthreads();
  if (threadIdx.x < 64) {
    int t = threadIdx.x;
    float v = sred[0][t] + sred[1][t] + sred[2][t] + sred[3][t];
    atomicAdd(&score[r0 + t], v);
  }
}

// ---- sigmoid + normalize; one block per b ----
__global__ void k_attn(const float* __restrict__ score, const float* __restrict__ b_score,
                       float* __restrict__ attn_out) {
  __shared__ float red[4];
  int b = blockIdx.x, t = threadIdx.x;
  float bs = b_score[0];
  float s[8];
  float sum = 0.f;
#pragma unroll
  for (int k = 0; k < 8; ++k) {
    float sc = score[(size_t)b * VLEN_SZ + k * 256 + t] + bs;
    s[k] = 1.0f / (1.0f + __expf(-sc));
    sum += s[k];
  }
#pragma unroll
  for (int off = 32; off; off >>= 1) sum += __shfl_xor(sum, off, 64);
  if ((t & 63) == 0) red[t >> 6] = sum;
  __syncthreads();
  float inv = 1.0f / (red[0] + red[1] + red[2] + red[3]);
#pragma unroll
  for (int k = 0; k < 8; ++k)
    attn_out[(size_t)b * VLEN_SZ + k * 256 + t] = s[k] * inv;
}

// ---- context[b,h] = sum_v attn[b,v]*value[b,v,h]; grid (32, 4 hTiles, 4 vChunks) ----
__global__ void k_ctx(const float* __restrict__ attn, const float* __restrict__ value,
                      float* __restrict__ context) {
  __shared__ float al[512];
  int b = blockIdx.x, ht = blockIdx.y, vc = blockIdx.z, t = threadIdx.x;
  int v0 = vc * 512;
  al[t] = attn[(size_t)b * VLEN_SZ + v0 + t];
  al[t + 256] = attn[(size_t)b * VLEN_SZ + v0 + 256 + t];
  __syncthreads();
  int h = ht * 256 + t;
  const float* vp = value + ((size_t)b * VLEN_SZ + v0) * H_SZ + h;
  float acc = 0.f;
#pragma unroll 8
  for (int v = 0; v < 512; ++v) acc += al[v] * vp[(size_t)v * H_SZ];
  atomicAdd(&context[(size_t)b * H_SZ + h], acc);
}

// ---- out[b,h] = b_out[h] + [context|query] . w_out[h,:]; one wave per output ----
__global__ void k_out(const float* __restrict__ context, const float* __restrict__ query,
                      const float* __restrict__ w_out, const float* __restrict__ b_out,
                      float* __restrict__ out) {
  int wid = blockIdx.x * 4 + (threadIdx.x >> 6);
  int lane = threadIdx.x & 63;
  int h = wid >> 5;
  int b = wid & 31;
  const f32x4* w4 = (const f32x4*)(w_out + (size_t)h * 2048);
  const f32x4* c4 = (const f32x4*)(context + (size_t)b * H_SZ);
  const f32x4* q4 = (const f32x4*)(query + (size_t)b * H_SZ);
  float acc = 0.f;
#pragma unroll
  for (int it = 0; it < 8; ++it) {
    int k4 = it * 64 + lane;
    f32x4 w = w4[k4];
    f32x4 c = (k4 < 256) ? c4[k4] : q4[k4 - 256];
    acc += w[0] * c[0] + w[1] * c[1] + w[2] * c[2] + w[3] * c[3];
  }
#pragma unroll
  for (int off = 32; off; off >>= 1) acc += __shfl_xor(acc, off, 64);
  if (lane == 0) out[(size_t)b * H_SZ + h] = acc + b_out[h];
}

extern "C" void kernel_launch(void* const* d_in, const int* in_sizes, int n_in,
                              void* d_out, int out_size, void* d_ws, size_t ws_size,
                              hipStream_t stream) {
  const float* query   = (const float*)d_in[0];
  const float* value   = (const float*)d_in[1];
  const float* prev    = (const float*)d_in[2];
  const float* conv_w  = (const float*)d_in[3];
  const float* conv_b  = (const float*)d_in[4];
  const float* w_loc   = (const float*)d_in[5];
  const float* w_q     = (const float*)d_in[6];
  const float* w_v     = (const float*)d_in[7];
  const float* bias    = (const float*)d_in[8];
  const float* w_score = (const float*)d_in[9];
  const float* b_score = (const float*)d_in[10];
  const float* w_out   = (const float*)d_in[11];
  const float* b_out   = (const float*)d_in[12];

  float* out  = (float*)d_out;                 // (B,1,H) = 32768 floats
  float* attn = out + B_SZ * H_SZ;             // (B,V)   = 65536 floats

  char* ws = (char*)d_ws;
  float* score   = (float*)(ws);               // 256 KB
  float* qpb     = (float*)(ws + (256 << 10)); // 128 KB
  float* context = (float*)(ws + (384 << 10)); // 128 KB
  short* wvb     = (short*)(ws + (512 << 10)); // 2 MB   bf16 w_v
  short* wlocb   = (short*)(ws + (2560 << 10));// 64 KB  bf16 w_loc
  short* cfb     = (short*)(ws + (3 << 20));   // 4 MB   bf16 conv features

  hipMemsetAsync(score, 0, B_SZ * VLEN_SZ * sizeof(float), stream);
  hipMemsetAsync(context, 0, B_SZ * H_SZ * sizeof(float), stream);

  k_f2bf<<<1024, 256, 0, stream>>>(w_v, wvb, (DIM_SZ * H_SZ) / 4);
  k_f2bf<<<32, 256, 0, stream>>>(w_loc, wlocb, (DIM_SZ * C_SZ) / 4);
  k_cf<<<(B_SZ * VLEN_SZ) / 256, 256, 0, stream>>>(prev, conv_w, conv_b, cfb);
  k_qpb<<<(B_SZ * DIM_SZ) / 4, 256, 0, stream>>>(query, w_q, bias, qpb);
  k_score<<<dim3(1024, 4), 256, 0, stream>>>(value, wvb, wlocb, cfb, qpb, w_score, score);
  k_attn<<<B_SZ, 256, 0, stream>>>(score, b_score, attn);
  k_ctx<<<dim3(B_SZ, 4, 4), 256, 0, stream>>>(attn, value, context);
  k_out<<<(B_SZ * H_SZ) / 4, 256, 0, stream>>>(context, query, w_out, b_out, out);
}

// Round 2
// 653.696 us; speedup vs baseline: 1.7163x; 1.7163x over previous
//
#include <hip/hip_runtime.h>
#include <hip/hip_bf16.h>
#include <math.h>

#define B_SZ 32
#define VLEN_SZ 2048
#define H_SZ 1024
#define DIM_SZ 1024
#define C_SZ 32

typedef float f32x4 __attribute__((ext_vector_type(4)));
typedef short s16x8 __attribute__((ext_vector_type(8)));
typedef short s16x4 __attribute__((ext_vector_type(4)));

__device__ __forceinline__ short f2bf(float f) {
  unsigned u = __float_as_uint(f);
  u = (u + 0x7fffu + ((u >> 16) & 1u)) >> 16;  // RNE
  return (short)u;
}

__device__ __forceinline__ float bf2f(short s) {
  return __uint_as_float(((unsigned)(unsigned short)s) << 16);
}

__device__ __forceinline__ float fast_tanh(float x) {
  float z = __expf(2.0f * x);
  return 1.0f - 2.0f / (z + 1.0f);
}

// async 16B global -> LDS (wave-uniform LDS base + lane*16)
__device__ __forceinline__ void ldg_lds16(const short* g, short* l) {
  __builtin_amdgcn_global_load_lds(
      (const __attribute__((address_space(1))) unsigned int*)g,
      (__attribute__((address_space(3))) unsigned int*)l, 16, 0, 0);
}

// ---- qp[b,d] = dot(query[b,:], w_q[d,:]) + bias[d]; one wave per output ----
__global__ void k_qpb(const float* __restrict__ query, const float* __restrict__ w_q,
                      const float* __restrict__ bias, float* __restrict__ qpb) {
  int wid = blockIdx.x * 4 + (threadIdx.x >> 6);
  int lane = threadIdx.x & 63;
  int d = wid >> 5;
  int b = wid & 31;
  const f32x4* q4 = (const f32x4*)(query + (size_t)b * H_SZ);
  const f32x4* w4 = (const f32x4*)(w_q + (size_t)d * H_SZ);
  float acc = 0.f;
#pragma unroll
  for (int it = 0; it < 4; ++it) {
    int k = it * 64 + lane;
    f32x4 a = q4[k], w = w4[k];
    acc += a[0] * w[0] + a[1] * w[1] + a[2] * w[2] + a[3] * w[3];
  }
#pragma unroll
  for (int off = 32; off; off >>= 1) acc += __shfl_xor(acc, off, 64);
  if (lane == 0) qpb[(size_t)b * DIM_SZ + d] = acc + bias[d];
}

// ---- fp32 -> bf16 cast, 4 elems/thread ----
__global__ void k_f2bf(const float* __restrict__ src, short* __restrict__ dst, int n4) {
  int i = blockIdx.x * blockDim.x + threadIdx.x;
  if (i >= n4) return;
  f32x4 v = ((const f32x4*)src)[i];
  s16x4 o;
  o[0] = f2bf(v[0]); o[1] = f2bf(v[1]); o[2] = f2bf(v[2]); o[3] = f2bf(v[3]);
  ((s16x4*)dst)[i] = o;
}

// ---- fp32 -> bf16 cast, 8 elems/thread (for the 64M-element value tensor) ----
__global__ void k_cast8(const float* __restrict__ src, short* __restrict__ dst) {
  size_t i = (size_t)blockIdx.x * 256 + threadIdx.x;  // s16x8 group index
  f32x4 x0 = ((const f32x4*)src)[2 * i];
  f32x4 x1 = ((const f32x4*)src)[2 * i + 1];
  s16x8 o;
  o[0] = f2bf(x0[0]); o[1] = f2bf(x0[1]); o[2] = f2bf(x0[2]); o[3] = f2bf(x0[3]);
  o[4] = f2bf(x1[0]); o[5] = f2bf(x1[1]); o[6] = f2bf(x1[2]); o[7] = f2bf(x1[3]);
  ((s16x8*)dst)[i] = o;
}

// ---- conv features cf[b,v,c] (bf16), k=3 pad=1 conv over prev_attn ----
__global__ void k_cf(const float* __restrict__ prev, const float* __restrict__ conv_w,
                     const float* __restrict__ conv_b, short* __restrict__ cfb) {
  int t = blockIdx.x * 256 + threadIdx.x;  // row index b*VLEN+v
  int v = t & (VLEN_SZ - 1);
  float p0 = prev[t];
  float pm = (v > 0) ? prev[t - 1] : 0.f;
  float pp = (v < VLEN_SZ - 1) ? prev[t + 1] : 0.f;
#pragma unroll
  for (int c = 0; c < C_SZ; ++c) {
    float f = conv_b[c] + pm * conv_w[c * 3 + 0] + p0 * conv_w[c * 3 + 1] + pp * conv_w[c * 3 + 2];
    cfb[(size_t)t * C_SZ + c] = f2bf(f);
  }
}

// ---- main fused kernel: m97-style 128x128 tile GEMM + lp K-step + tanh + score ----
// block: 4 waves, each owning a 64x64 acc tile (2x2 wave grid).
// grid (8 n-tiles, 512 m-tiles) - n fastest so concurrent blocks share A rows.
__global__ __launch_bounds__(256, 3) void k_score(
    const short* __restrict__ vb, const short* __restrict__ wvb,
    const short* __restrict__ wlocb, const short* __restrict__ cfb,
    const float* __restrict__ qpb, const float* __restrict__ w_score,
    float* __restrict__ score) {
  __shared__ short As[128 * 32];   // 8 KB, [m][32k] with XOR-swizzled 8-elem chunks
  __shared__ short Bs[128 * 32];   // 8 KB
  __shared__ float sred[4][64];

  int t = threadIdx.x;
  int w = t >> 6, l = t & 63;
  int q = l >> 4, l16 = l & 15;
  int nt = blockIdx.x;             // 0..7
  int mt = blockIdx.y;             // 0..511
  int row0 = mt * 128;             // global row base (b*VLEN+v)
  int d0 = nt * 128;
  int b = row0 >> 11;              // VLEN = 2048
  int wm = w >> 1, wn = w & 1;

  // staging decomposition: one instr = 16 rows x 32 k (1 KB). lane l ->
  // row lr = l>>2, position chunk l&3; CONTENT chunk = (l&3) ^ ((l>>3)&3)
  // so that chunk c of row m lives at position c ^ ((m>>1)&3)  (2-way reads)
  int lr = l >> 2;
  int kc = ((l & 3) ^ ((l >> 3) & 3)) * 8;  // element offset within BK=32

  const short* gA0 = vb + (size_t)(row0 + 32 * w + lr) * H_SZ + kc;
  const short* gA1 = vb + (size_t)(row0 + 32 * w + 16 + lr) * H_SZ + kc;
  const short* gB0 = wvb + (size_t)(d0 + 32 * w + lr) * H_SZ + kc;
  const short* gB1 = wvb + (size_t)(d0 + 32 * w + 16 + lr) * H_SZ + kc;
  short* lA0 = As + (32 * w) * 32;
  short* lA1 = As + (32 * w + 16) * 32;
  short* lB0 = Bs + (32 * w) * 32;
  short* lB1 = Bs + (32 * w + 16) * 32;

  // fragment-read swizzled chunk position (uniform over i since i*16>>1 is mult of 8)
  int posA = (q ^ ((l16 >> 1) & 3)) * 8;

  f32x4 acc[4][4];
#pragma unroll
  for (int i = 0; i < 4; ++i)
#pragma unroll
    for (int j = 0; j < 4; ++j) acc[i][j] = (f32x4){0.f, 0.f, 0.f, 0.f};

  for (int kt = 0; kt <= 32; ++kt) {
    if (kt < 32) {
      int k0 = kt * 32;
      ldg_lds16(gA0 + k0, lA0);
      ldg_lds16(gA1 + k0, lA1);
      ldg_lds16(gB0 + k0, lB0);
      ldg_lds16(gB1 + k0, lB1);
    } else {
      // location-feature K-step: A = cf (row stride 32), B = w_loc
      ldg_lds16(cfb + (size_t)(row0 + 32 * w + lr) * C_SZ + kc, lA0);
      ldg_lds16(cfb + (size_t)(row0 + 32 * w + 16 + lr) * C_SZ + kc, lA1);
      ldg_lds16(wlocb + (size_t)(d0 + 32 * w + lr) * C_SZ + kc, lB0);
      ldg_lds16(wlocb + (size_t)(d0 + 32 * w + 16 + lr) * C_SZ + kc, lB1);
    }
    __syncthreads();  // drains vmcnt, staging complete

    s16x8 a[4], bb[4];
#pragma unroll
    for (int i = 0; i < 4; ++i)
      a[i] = *(const s16x8*)(As + (wm * 64 + i * 16 + l16) * 32 + posA);
#pragma unroll
    for (int j = 0; j < 4; ++j)
      bb[j] = *(const s16x8*)(Bs + (wn * 64 + j * 16 + l16) * 32 + posA);
#pragma unroll
    for (int i = 0; i < 4; ++i)
#pragma unroll
      for (int j = 0; j < 4; ++j)
        acc[i][j] = __builtin_amdgcn_mfma_f32_16x16x32_bf16(a[i], bb[j], acc[i][j], 0, 0, 0);
    __syncthreads();  // before next stage overwrites
  }

  // epilogue: e = tanh(acc + qp[d]) (qp already includes bias), score += e.w_score
  float qv[4], wv[4];
#pragma unroll
  for (int j = 0; j < 4; ++j) {
    int d = d0 + wn * 64 + j * 16 + l16;
    qv[j] = qpb[(size_t)b * DIM_SZ + d];
    wv[j] = w_score[d];
  }

#pragma unroll
  for (int i = 0; i < 4; ++i) {
#pragma unroll
    for (int r = 0; r < 4; ++r) {
      float part = 0.f;
#pragma unroll
      for (int j = 0; j < 4; ++j)
        part += fast_tanh(acc[i][j][r] + qv[j]) * wv[j];
      part += __shfl_xor(part, 1);
      part += __shfl_xor(part, 2);
      part += __shfl_xor(part, 4);
      part += __shfl_xor(part, 8);
      if (l16 == 0) sred[w][i * 16 + q * 4 + r] = part;
    }
  }
  __syncthreads();
  if (t < 128) {
    int half = t >> 6;
    float v = sred[half * 2][t & 63] + sred[half * 2 + 1][t & 63];
    atomicAdd(&score[row0 + t], v);
  }
}

// ---- sigmoid + normalize; one block per b ----
__global__ void k_attn(const float* __restrict__ score, const float* __restrict__ b_score,
                       float* __restrict__ attn_out) {
  __shared__ float red[4];
  int b = blockIdx.x, t = threadIdx.x;
  float bs = b_score[0];
  float s[8];
  float sum = 0.f;
#pragma unroll
  for (int k = 0; k < 8; ++k) {
    float sc = score[(size_t)b * VLEN_SZ + k * 256 + t] + bs;
    s[k] = 1.0f / (1.0f + __expf(-sc));
    sum += s[k];
  }
#pragma unroll
  for (int off = 32; off; off >>= 1) sum += __shfl_xor(sum, off, 64);
  if ((t & 63) == 0) red[t >> 6] = sum;
  __syncthreads();
  float inv = 1.0f / (red[0] + red[1] + red[2] + red[3]);
#pragma unroll
  for (int k = 0; k < 8; ++k)
    attn_out[(size_t)b * VLEN_SZ + k * 256 + t] = s[k] * inv;
}

// ---- context[b,h] = sum_v attn[b,v]*value[b,v,h] (bf16 value); grid (32,4,4) ----
__global__ void k_ctx(const float* __restrict__ attn, const short* __restrict__ vb,
                      float* __restrict__ context) {
  __shared__ float al[512];
  int b = blockIdx.x, ht = blockIdx.y, vc = blockIdx.z, t = threadIdx.x;
  int v0 = vc * 512;
  al[t] = attn[(size_t)b * VLEN_SZ + v0 + t];
  al[t + 256] = attn[(size_t)b * VLEN_SZ + v0 + 256 + t];
  __syncthreads();
  int h = ht * 256 + t;
  const short* vp = vb + ((size_t)b * VLEN_SZ + v0) * H_SZ + h;
  float acc = 0.f;
#pragma unroll 8
  for (int v = 0; v < 512; ++v) acc += al[v] * bf2f(vp[(size_t)v * H_SZ]);
  atomicAdd(&context[(size_t)b * H_SZ + h], acc);
}

// ---- out[b,h] = b_out[h] + [context|query] . w_out[h,:]; one wave per output ----
__global__ void k_out(const float* __restrict__ context, const float* __restrict__ query,
                      const float* __restrict__ w_out, const float* __restrict__ b_out,
                      float* __restrict__ out) {
  int wid = blockIdx.x * 4 + (threadIdx.x >> 6);
  int lane = threadIdx.x & 63;
  int h = wid >> 5;
  int b = wid & 31;
  const f32x4* w4 = (const f32x4*)(w_out + (size_t)h * 2048);
  const f32x4* c4 = (const f32x4*)(context + (size_t)b * H_SZ);
  const f32x4* q4 = (const f32x4*)(query + (size_t)b * H_SZ);
  float acc = 0.f;
#pragma unroll
  for (int it = 0; it < 8; ++it) {
    int k4 = it * 64 + lane;
    f32x4 w = w4[k4];
    f32x4 c = (k4 < 256) ? c4[k4] : q4[k4 - 256];
    acc += w[0] * c[0] + w[1] * c[1] + w[2] * c[2] + w[3] * c[3];
  }
#pragma unroll
  for (int off = 32; off; off >>= 1) acc += __shfl_xor(acc, off, 64);
  if (lane == 0) out[(size_t)b * H_SZ + h] = acc + b_out[h];
}

extern "C" void kernel_launch(void* const* d_in, const int* in_sizes, int n_in,
                              void* d_out, int out_size, void* d_ws, size_t ws_size,
                              hipStream_t stream) {
  const float* query   = (const float*)d_in[0];
  const float* value   = (const float*)d_in[1];
  const float* prev    = (const float*)d_in[2];
  const float* conv_w  = (const float*)d_in[3];
  const float* conv_b  = (const float*)d_in[4];
  const float* w_loc   = (const float*)d_in[5];
  const float* w_q     = (const float*)d_in[6];
  const float* w_v     = (const float*)d_in[7];
  const float* bias    = (const float*)d_in[8];
  const float* w_score = (const float*)d_in[9];
  const float* b_score = (const float*)d_in[10];
  const float* w_out   = (const float*)d_in[11];
  const float* b_out   = (const float*)d_in[12];

  float* out  = (float*)d_out;                 // (B,1,H) = 32768 floats
  float* attn = out + B_SZ * H_SZ;             // (B,V)   = 65536 floats

  char* ws = (char*)d_ws;
  float* score   = (float*)(ws);               // 256 KB
  float* qpb     = (float*)(ws + (256 << 10)); // 128 KB
  float* context = (float*)(ws + (384 << 10)); // 128 KB
  short* wvb     = (short*)(ws + (512 << 10)); // 2 MB   bf16 w_v
  short* wlocb   = (short*)(ws + (2560 << 10));// 64 KB  bf16 w_loc
  short* cfb     = (short*)(ws + (3 << 20));   // 4 MB   bf16 conv features
  short* vb      = (short*)(ws + (8 << 20));   // 128 MB bf16 value

  hipMemsetAsync(score, 0, B_SZ * VLEN_SZ * sizeof(float), stream);
  hipMemsetAsync(context, 0, B_SZ * H_SZ * sizeof(float), stream);

  k_cast8<<<(B_SZ * VLEN_SZ * H_SZ) / (256 * 8), 256, 0, stream>>>(value, vb);
  k_f2bf<<<1024, 256, 0, stream>>>(w_v, wvb, (DIM_SZ * H_SZ) / 4);
  k_f2bf<<<32, 256, 0, stream>>>(w_loc, wlocb, (DIM_SZ * C_SZ) / 4);
  k_cf<<<(B_SZ * VLEN_SZ) / 256, 256, 0, stream>>>(prev, conv_w, conv_b, cfb);
  k_qpb<<<(B_SZ * DIM_SZ) / 4, 256, 0, stream>>>(query, w_q, bias, qpb);
  k_score<<<dim3(8, 512), 256, 0, stream>>>(vb, wvb, wlocb, cfb, qpb, w_score, score);
  k_attn<<<B_SZ, 256, 0, stream>>>(score, b_score, attn);
  k_ctx<<<dim3(B_SZ, 4, 4), 256, 0, stream>>>(attn, vb, context);
  k_out<<<(B_SZ * H_SZ) / 4, 256, 0, stream>>>(context, query, w_out, b_out, out);
}

// Round 3
// 637.701 us; speedup vs baseline: 1.7594x; 1.0251x over previous
//
#include <hip/hip_runtime.h>
#include <hip/hip_bf16.h>
#include <math.h>

#define B_SZ 32
#define VLEN_SZ 2048
#define H_SZ 1024
#define DIM_SZ 1024
#define C_SZ 32

typedef float f32x4 __attribute__((ext_vector_type(4)));
typedef short s16x8 __attribute__((ext_vector_type(8)));
typedef short s16x4 __attribute__((ext_vector_type(4)));

__device__ __forceinline__ short f2bf(float f) {
  unsigned u = __float_as_uint(f);
  u = (u + 0x7fffu + ((u >> 16) & 1u)) >> 16;  // RNE
  return (short)u;
}

__device__ __forceinline__ float bf2f(short s) {
  return __uint_as_float(((unsigned)(unsigned short)s) << 16);
}

__device__ __forceinline__ float fast_tanh(float x) {
  float z = __expf(2.0f * x);
  return 1.0f - 2.0f / (z + 1.0f);
}

// async 16B global -> LDS (wave-uniform LDS base + lane*16)
__device__ __forceinline__ void ldg_lds16(const short* g, short* l) {
  __builtin_amdgcn_global_load_lds(
      (const __attribute__((address_space(1))) unsigned int*)g,
      (__attribute__((address_space(3))) unsigned int*)l, 16, 0, 0);
}

// ---- fused prep: qpb + conv-features + weight casts + value cast + zeroing ----
// role by block range:
//   [0,8192)      qp[b,d] = dot(query[b],w_q[d]) + bias[d]   (one wave per (b,d))
//   [8192,8448)   conv features cf[b,v,c] bf16
//   [8448,8480)   w_loc -> bf16
//   [8480,9504)   w_v   -> bf16
//   [9504,9568)   zero score
//   [9568,9600)   zero context
//   [9600,42368)  value -> bf16 (8 elems/thread)
__global__ __launch_bounds__(256) void k_prep(
    const float* __restrict__ query, const float* __restrict__ w_q,
    const float* __restrict__ bias, const float* __restrict__ prev,
    const float* __restrict__ conv_w, const float* __restrict__ conv_b,
    const float* __restrict__ w_loc, const float* __restrict__ w_v,
    const float* __restrict__ value,
    float* __restrict__ qpb, short* __restrict__ cfb, short* __restrict__ wlocb,
    short* __restrict__ wvb, short* __restrict__ vb,
    float* __restrict__ score, float* __restrict__ context) {
  int bid = blockIdx.x;
  int t = threadIdx.x;
  if (bid < 8192) {
    int wid = bid * 4 + (t >> 6);
    int lane = t & 63;
    int d = wid >> 5;
    int b = wid & 31;
    const f32x4* q4 = (const f32x4*)(query + (size_t)b * H_SZ);
    const f32x4* w4 = (const f32x4*)(w_q + (size_t)d * H_SZ);
    float acc = 0.f;
#pragma unroll
    for (int it = 0; it < 4; ++it) {
      int k = it * 64 + lane;
      f32x4 a = q4[k], w = w4[k];
      acc += a[0] * w[0] + a[1] * w[1] + a[2] * w[2] + a[3] * w[3];
    }
#pragma unroll
    for (int off = 32; off; off >>= 1) acc += __shfl_xor(acc, off, 64);
    if (lane == 0) qpb[(size_t)b * DIM_SZ + d] = acc + bias[d];
  } else if (bid < 8448) {
    int r = (bid - 8192) * 256 + t;  // row index b*VLEN+v
    int v = r & (VLEN_SZ - 1);
    float p0 = prev[r];
    float pm = (v > 0) ? prev[r - 1] : 0.f;
    float pp = (v < VLEN_SZ - 1) ? prev[r + 1] : 0.f;
#pragma unroll
    for (int c = 0; c < C_SZ; ++c) {
      float f = conv_b[c] + pm * conv_w[c * 3 + 0] + p0 * conv_w[c * 3 + 1] + pp * conv_w[c * 3 + 2];
      cfb[(size_t)r * C_SZ + c] = f2bf(f);
    }
  } else if (bid < 8480) {
    int i = (bid - 8448) * 256 + t;  // n4 = 8192
    f32x4 v = ((const f32x4*)w_loc)[i];
    s16x4 o;
    o[0] = f2bf(v[0]); o[1] = f2bf(v[1]); o[2] = f2bf(v[2]); o[3] = f2bf(v[3]);
    ((s16x4*)wlocb)[i] = o;
  } else if (bid < 9504) {
    int i = (bid - 8480) * 256 + t;  // n4 = 262144
    f32x4 v = ((const f32x4*)w_v)[i];
    s16x4 o;
    o[0] = f2bf(v[0]); o[1] = f2bf(v[1]); o[2] = f2bf(v[2]); o[3] = f2bf(v[3]);
    ((s16x4*)wvb)[i] = o;
  } else if (bid < 9568) {
    int i = (bid - 9504) * 256 + t;  // 16384 f32x4
    ((f32x4*)score)[i] = (f32x4){0.f, 0.f, 0.f, 0.f};
  } else if (bid < 9600) {
    int i = (bid - 9568) * 256 + t;  // 8192 f32x4
    ((f32x4*)context)[i] = (f32x4){0.f, 0.f, 0.f, 0.f};
  } else {
    size_t i = (size_t)(bid - 9600) * 256 + t;  // s16x8 group
    f32x4 x0 = ((const f32x4*)value)[2 * i];
    f32x4 x1 = ((const f32x4*)value)[2 * i + 1];
    s16x8 o;
    o[0] = f2bf(x0[0]); o[1] = f2bf(x0[1]); o[2] = f2bf(x0[2]); o[3] = f2bf(x0[3]);
    o[4] = f2bf(x1[0]); o[5] = f2bf(x1[1]); o[6] = f2bf(x1[2]); o[7] = f2bf(x1[3]);
    ((s16x8*)vb)[i] = o;
  }
}

// ---- main fused kernel: 128x128 tile GEMM + lp K-step + tanh + score ----
// 1-D grid 4096 with XCD-aware decomposition: x = bid%8 is the XCD under
// round-robin dispatch; XCD x owns mt in [x*64, x*64+64) and its 8 nt blocks
// per mt are consecutive in its dispatch sequence -> A-tile fetched by ONE
// XCD's L2, once. Working set/XCD ~3 MB < 4 MB L2.
__global__ __launch_bounds__(256, 3) void k_score(
    const short* __restrict__ vb, const short* __restrict__ wvb,
    const short* __restrict__ wlocb, const short* __restrict__ cfb,
    const float* __restrict__ qpb, const float* __restrict__ w_score,
    float* __restrict__ score) {
  __shared__ short As[128 * 32];   // 8 KB, [m][32k] with XOR-swizzled 8-elem chunks
  __shared__ short Bs[128 * 32];   // 8 KB
  __shared__ float sred[4][64];

  int t = threadIdx.x;
  int w = t >> 6, l = t & 63;
  int q = l >> 4, l16 = l & 15;
  int bid = blockIdx.x;
  int x = bid & 7;
  int j = bid >> 3;
  int nt = j & 7;                  // 0..7
  int mt = x * 64 + (j >> 3);      // 0..511
  int row0 = mt * 128;             // global row base (b*VLEN+v)
  int d0 = nt * 128;
  int b = row0 >> 11;              // VLEN = 2048
  int wm = w >> 1, wn = w & 1;

  // staging: one instr = 16 rows x 32 k (1 KB). lane l -> row lr = l>>2,
  // position chunk l&3; CONTENT chunk = (l&3) ^ ((l>>3)&3) so chunk c of
  // row m lives at position c ^ ((m>>1)&3)  (2-way fragment reads = free)
  int lr = l >> 2;
  int kc = ((l & 3) ^ ((l >> 3) & 3)) * 8;

  const short* gA0 = vb + (size_t)(row0 + 32 * w + lr) * H_SZ + kc;
  const short* gA1 = vb + (size_t)(row0 + 32 * w + 16 + lr) * H_SZ + kc;
  const short* gB0 = wvb + (size_t)(d0 + 32 * w + lr) * H_SZ + kc;
  const short* gB1 = wvb + (size_t)(d0 + 32 * w + 16 + lr) * H_SZ + kc;
  short* lA0 = As + (32 * w) * 32;
  short* lA1 = As + (32 * w + 16) * 32;
  short* lB0 = Bs + (32 * w) * 32;
  short* lB1 = Bs + (32 * w + 16) * 32;

  int posA = (q ^ ((l16 >> 1) & 3)) * 8;

  f32x4 acc[4][4];
#pragma unroll
  for (int i = 0; i < 4; ++i)
#pragma unroll
    for (int jj = 0; jj < 4; ++jj) acc[i][jj] = (f32x4){0.f, 0.f, 0.f, 0.f};

  for (int kt = 0; kt <= 32; ++kt) {
    if (kt < 32) {
      int k0 = kt * 32;
      ldg_lds16(gA0 + k0, lA0);
      ldg_lds16(gA1 + k0, lA1);
      ldg_lds16(gB0 + k0, lB0);
      ldg_lds16(gB1 + k0, lB1);
    } else {
      // location-feature K-step: A = cf (row stride 32), B = w_loc
      ldg_lds16(cfb + (size_t)(row0 + 32 * w + lr) * C_SZ + kc, lA0);
      ldg_lds16(cfb + (size_t)(row0 + 32 * w + 16 + lr) * C_SZ + kc, lA1);
      ldg_lds16(wlocb + (size_t)(d0 + 32 * w + lr) * C_SZ + kc, lB0);
      ldg_lds16(wlocb + (size_t)(d0 + 32 * w + 16 + lr) * C_SZ + kc, lB1);
    }
    __syncthreads();

    s16x8 a[4], bb[4];
#pragma unroll
    for (int i = 0; i < 4; ++i)
      a[i] = *(const s16x8*)(As + (wm * 64 + i * 16 + l16) * 32 + posA);
#pragma unroll
    for (int jj = 0; jj < 4; ++jj)
      bb[jj] = *(const s16x8*)(Bs + (wn * 64 + jj * 16 + l16) * 32 + posA);
#pragma unroll
    for (int i = 0; i < 4; ++i)
#pragma unroll
      for (int jj = 0; jj < 4; ++jj)
        acc[i][jj] = __builtin_amdgcn_mfma_f32_16x16x32_bf16(a[i], bb[jj], acc[i][jj], 0, 0, 0);
    __syncthreads();
  }

  // epilogue: e = tanh(acc + qp[d]) (qp includes bias), score += e.w_score
  float qv[4], wv[4];
#pragma unroll
  for (int jj = 0; jj < 4; ++jj) {
    int d = d0 + wn * 64 + jj * 16 + l16;
    qv[jj] = qpb[(size_t)b * DIM_SZ + d];
    wv[jj] = w_score[d];
  }

#pragma unroll
  for (int i = 0; i < 4; ++i) {
#pragma unroll
    for (int r = 0; r < 4; ++r) {
      float part = 0.f;
#pragma unroll
      for (int jj = 0; jj < 4; ++jj)
        part += fast_tanh(acc[i][jj][r] + qv[jj]) * wv[jj];
      part += __shfl_xor(part, 1);
      part += __shfl_xor(part, 2);
      part += __shfl_xor(part, 4);
      part += __shfl_xor(part, 8);
      if (l16 == 0) sred[w][i * 16 + q * 4 + r] = part;
    }
  }
  __syncthreads();
  if (t < 128) {
    int half = t >> 6;
    float v = sred[half * 2][t & 63] + sred[half * 2 + 1][t & 63];
    atomicAdd(&score[row0 + t], v);
  }
}

// ---- fused sigmoid-normalize + context partial; grid (32 b, 4 vc) ----
// phase 1: full attn row for b from score (recomputed per block, cheap);
// vc==0 blocks also write the attn output rows.
// phase 2: context accumulation, 8 h-cols/thread (s16x8 loads), atomics.
__global__ __launch_bounds__(256) void k_ctx(
    const float* __restrict__ score, const float* __restrict__ b_score,
    const short* __restrict__ vb, float* __restrict__ attn_out,
    float* __restrict__ context) {
  __shared__ float als[VLEN_SZ];
  __shared__ float red[4];
  int b = blockIdx.x, vc = blockIdx.y, t = threadIdx.x;
  float bs = b_score[0];
  float sv[8];
  float lsum = 0.f;
  int v0 = t * 8;
#pragma unroll
  for (int k = 0; k < 8; ++k) {
    float ps = score[(size_t)b * VLEN_SZ + v0 + k] + bs;
    float s = 1.0f / (1.0f + __expf(-ps));
    sv[k] = s;
    lsum += s;
    als[v0 + k] = s;
  }
#pragma unroll
  for (int off = 32; off; off >>= 1) lsum += __shfl_xor(lsum, off, 64);
  if ((t & 63) == 0) red[t >> 6] = lsum;
  __syncthreads();
  float inv = 1.0f / (red[0] + red[1] + red[2] + red[3]);
  if (vc == 0) {
#pragma unroll
    for (int k = 0; k < 8; ++k)
      attn_out[(size_t)b * VLEN_SZ + v0 + k] = sv[k] * inv;
  }

  int p = t >> 7, tt = t & 127, h0 = tt * 8;
  int vbase = vc * 512 + p * 256;
  const short* vp = vb + ((size_t)b * VLEN_SZ + vbase) * H_SZ + h0;
  const float* av = als + vbase;
  float acc[8] = {0.f, 0.f, 0.f, 0.f, 0.f, 0.f, 0.f, 0.f};
#pragma unroll 4
  for (int v = 0; v < 256; ++v) {
    s16x8 xv = *(const s16x8*)(vp + (size_t)v * H_SZ);
    float a = av[v];
#pragma unroll
    for (int k = 0; k < 8; ++k) acc[k] += a * bf2f(xv[k]);
  }
#pragma unroll
  for (int k = 0; k < 8; ++k)
    atomicAdd(&context[(size_t)b * H_SZ + h0 + k], acc[k] * inv);
}

// ---- out[b,h] = b_out[h] + [context|query] . w_out[h,:]; one wave per output ----
__global__ void k_out(const float* __restrict__ context, const float* __restrict__ query,
                      const float* __restrict__ w_out, const float* __restrict__ b_out,
                      float* __restrict__ out) {
  int wid = blockIdx.x * 4 + (threadIdx.x >> 6);
  int lane = threadIdx.x & 63;
  int h = wid >> 5;
  int b = wid & 31;
  const f32x4* w4 = (const f32x4*)(w_out + (size_t)h * 2048);
  const f32x4* c4 = (const f32x4*)(context + (size_t)b * H_SZ);
  const f32x4* q4 = (const f32x4*)(query + (size_t)b * H_SZ);
  float acc = 0.f;
#pragma unroll
  for (int it = 0; it < 8; ++it) {
    int k4 = it * 64 + lane;
    f32x4 w = w4[k4];
    f32x4 c = (k4 < 256) ? c4[k4] : q4[k4 - 256];
    acc += w[0] * c[0] + w[1] * c[1] + w[2] * c[2] + w[3] * c[3];
  }
#pragma unroll
  for (int off = 32; off; off >>= 1) acc += __shfl_xor(acc, off, 64);
  if (lane == 0) out[(size_t)b * H_SZ + h] = acc + b_out[h];
}

extern "C" void kernel_launch(void* const* d_in, const int* in_sizes, int n_in,
                              void* d_out, int out_size, void* d_ws, size_t ws_size,
                              hipStream_t stream) {
  const float* query   = (const float*)d_in[0];
  const float* value   = (const float*)d_in[1];
  const float* prev    = (const float*)d_in[2];
  const float* conv_w  = (const float*)d_in[3];
  const float* conv_b  = (const float*)d_in[4];
  const float* w_loc   = (const float*)d_in[5];
  const float* w_q     = (const float*)d_in[6];
  const float* w_v     = (const float*)d_in[7];
  const float* bias    = (const float*)d_in[8];
  const float* w_score = (const float*)d_in[9];
  const float* b_score = (const float*)d_in[10];
  const float* w_out   = (const float*)d_in[11];
  const float* b_out   = (const float*)d_in[12];

  float* out  = (float*)d_out;                 // (B,1,H) = 32768 floats
  float* attn = out + B_SZ * H_SZ;             // (B,V)   = 65536 floats

  char* ws = (char*)d_ws;
  float* score   = (float*)(ws);               // 256 KB
  float* qpb     = (float*)(ws + (256 << 10)); // 128 KB
  float* context = (float*)(ws + (384 << 10)); // 128 KB
  short* wvb     = (short*)(ws + (512 << 10)); // 2 MB   bf16 w_v
  short* wlocb   = (short*)(ws + (2560 << 10));// 64 KB  bf16 w_loc
  short* cfb     = (short*)(ws + (3 << 20));   // 4 MB   bf16 conv features
  short* vb      = (short*)(ws + (8 << 20));   // 128 MB bf16 value

  k_prep<<<42368, 256, 0, stream>>>(query, w_q, bias, prev, conv_w, conv_b,
                                    w_loc, w_v, value,
                                    qpb, cfb, wlocb, wvb, vb, score, context);
  k_score<<<4096, 256, 0, stream>>>(vb, wvb, wlocb, cfb, qpb, w_score, score);
  k_ctx<<<dim3(B_SZ, 4), 256, 0, stream>>>(score, b_score, vb, attn, context);
  k_out<<<(B_SZ * H_SZ) / 4, 256, 0, stream>>>(context, query, w_out, b_out, out);
}

// Round 4
// 632.408 us; speedup vs baseline: 1.7741x; 1.0084x over previous
//
#include <hip/hip_runtime.h>
#include <hip/hip_bf16.h>
#include <math.h>

#define B_SZ 32
#define VLEN_SZ 2048
#define H_SZ 1024
#define DIM_SZ 1024
#define C_SZ 32

typedef float f32x4 __attribute__((ext_vector_type(4)));
typedef short s16x8 __attribute__((ext_vector_type(8)));
typedef short s16x4 __attribute__((ext_vector_type(4)));
typedef unsigned int u32x4 __attribute__((ext_vector_type(4)));

__device__ __forceinline__ short f2bf(float f) {
  unsigned u = __float_as_uint(f);
  u = (u + 0x7fffu + ((u >> 16) & 1u)) >> 16;  // RNE
  return (short)u;
}

__device__ __forceinline__ float bf2f(short s) {
  return __uint_as_float(((unsigned)(unsigned short)s) << 16);
}

// pack hi16(a), hi16(b) -> (bf16(b)<<16)|bf16(a)  [truncation], 1 instr
__device__ __forceinline__ unsigned pack2(float a, float b) {
  return __builtin_amdgcn_perm(__float_as_uint(b), __float_as_uint(a), 0x07060302u);
}

__device__ __forceinline__ float fast_tanh(float x) {
  float z = __expf(2.0f * x);
  return 1.0f - 2.0f / (z + 1.0f);
}

// async 16B global -> LDS (wave-uniform LDS base + lane*16)
__device__ __forceinline__ void ldg_lds16(const void* g, void* l) {
  __builtin_amdgcn_global_load_lds(
      (const __attribute__((address_space(1))) unsigned int*)g,
      (__attribute__((address_space(3))) unsigned int*)l, 16, 0, 0);
}

// ---- fused prep: qpb + conv-features(fp32) + weight casts + zeroing ----
// role by block range:
//   [0,8192)      qp[b,d] = dot(query[b],w_q[d]) + bias[d]   (one wave per (b,d))
//   [8192,8448)   conv features cf[b,v,c] fp32 (f32x4 stores)
//   [8448,8480)   w_loc -> bf16
//   [8480,9504)   w_v   -> bf16
//   [9504,9568)   zero score
//   [9568,9600)   zero context
__global__ __launch_bounds__(256) void k_prep(
    const float* __restrict__ query, const float* __restrict__ w_q,
    const float* __restrict__ bias, const float* __restrict__ prev,
    const float* __restrict__ conv_w, const float* __restrict__ conv_b,
    const float* __restrict__ w_loc, const float* __restrict__ w_v,
    float* __restrict__ qpb, float* __restrict__ cff, short* __restrict__ wlocb,
    short* __restrict__ wvb, float* __restrict__ score, float* __restrict__ context) {
  int bid = blockIdx.x;
  int t = threadIdx.x;
  if (bid < 8192) {
    int wid = bid * 4 + (t >> 6);
    int lane = t & 63;
    int d = wid >> 5;
    int b = wid & 31;
    const f32x4* q4 = (const f32x4*)(query + (size_t)b * H_SZ);
    const f32x4* w4 = (const f32x4*)(w_q + (size_t)d * H_SZ);
    float acc = 0.f;
#pragma unroll
    for (int it = 0; it < 4; ++it) {
      int k = it * 64 + lane;
      f32x4 a = q4[k], w = w4[k];
      acc += a[0] * w[0] + a[1] * w[1] + a[2] * w[2] + a[3] * w[3];
    }
#pragma unroll
    for (int off = 32; off; off >>= 1) acc += __shfl_xor(acc, off, 64);
    if (lane == 0) qpb[(size_t)b * DIM_SZ + d] = acc + bias[d];
  } else if (bid < 8448) {
    int r = (bid - 8192) * 256 + t;  // row index b*VLEN+v
    int v = r & (VLEN_SZ - 1);
    float p0 = prev[r];
    float pm = (v > 0) ? prev[r - 1] : 0.f;
    float pp = (v < VLEN_SZ - 1) ? prev[r + 1] : 0.f;
    float o[C_SZ];
#pragma unroll
    for (int c = 0; c < C_SZ; ++c)
      o[c] = conv_b[c] + pm * conv_w[c * 3 + 0] + p0 * conv_w[c * 3 + 1] + pp * conv_w[c * 3 + 2];
    f32x4* dst = (f32x4*)(cff + (size_t)r * C_SZ);
#pragma unroll
    for (int g = 0; g < 8; ++g)
      dst[g] = (f32x4){o[4 * g], o[4 * g + 1], o[4 * g + 2], o[4 * g + 3]};
  } else if (bid < 8480) {
    int i = (bid - 8448) * 256 + t;  // n4 = 8192
    f32x4 v = ((const f32x4*)w_loc)[i];
    s16x4 o;
    o[0] = f2bf(v[0]); o[1] = f2bf(v[1]); o[2] = f2bf(v[2]); o[3] = f2bf(v[3]);
    ((s16x4*)wlocb)[i] = o;
  } else if (bid < 9504) {
    int i = (bid - 8480) * 256 + t;  // n4 = 262144
    f32x4 v = ((const f32x4*)w_v)[i];
    s16x4 o;
    o[0] = f2bf(v[0]); o[1] = f2bf(v[1]); o[2] = f2bf(v[2]); o[3] = f2bf(v[3]);
    ((s16x4*)wvb)[i] = o;
  } else if (bid < 9568) {
    int i = (bid - 9504) * 256 + t;  // 16384 f32x4
    ((f32x4*)score)[i] = (f32x4){0.f, 0.f, 0.f, 0.f};
  } else {
    int i = (bid - 9568) * 256 + t;  // 8192 f32x4
    ((f32x4*)context)[i] = (f32x4){0.f, 0.f, 0.f, 0.f};
  }
}

// ---- main fused kernel: 128x128 tile GEMM (fp32 A staged, bf16 MFMA) ----
// A (value, fp32) staged via global_load_lds into As [128 rows x 32 fp32],
// chunk c (16B) of row m stored at position c ^ (m&7) -> conflict-floor reads.
// Packed to bf16 fragments in-register via v_perm (truncation).
// XCD-aware 1-D grid 4096: x=bid&7 owns mt range, nt consecutive -> L2 reuse.
__global__ __launch_bounds__(256, 4) void k_score(
    const float* __restrict__ value, const short* __restrict__ wvb,
    const short* __restrict__ wlocb, const float* __restrict__ cff,
    const float* __restrict__ qpb, const float* __restrict__ w_score,
    float* __restrict__ score) {
  __shared__ float As[128 * 32];   // 16 KB fp32, swizzled 16B chunks
  __shared__ short Bs[128 * 32];   // 8 KB bf16
  __shared__ float sred[4][64];

  int t = threadIdx.x;
  int w = t >> 6, l = t & 63;
  int q = l >> 4, l16 = l & 15;
  int bid = blockIdx.x;
  int x = bid & 7;
  int j = bid >> 3;
  int nt = j & 7;                  // 0..7
  int mt = x * 64 + (j >> 3);      // 0..511
  int row0 = mt * 128;             // global row base (b*VLEN+v)
  int d0 = nt * 128;
  int b = row0 >> 11;              // VLEN = 2048
  int wm = w >> 1, wn = w & 1;

  // A staging: 4 instrs/wave, each 8 rows x 32 fp32 (1 KB). lane i ->
  // row (i>>3), pos (i&7), content chunk c = (i&7)^(i>>3).
  int ar = l >> 3;                       // 0..7
  int ac = (l & 7) ^ ar;                 // content chunk 0..7 (4 floats)
  const float* gA[4];
  float* lA[4];
#pragma unroll
  for (int s = 0; s < 4; ++s) {
    gA[s] = value + (size_t)(row0 + 32 * w + 8 * s + ar) * H_SZ + ac * 4;
    lA[s] = As + (32 * w + 8 * s) * 32;
  }
  // B staging: 2 instrs/wave, 16 rows x 32 bf16 (1 KB). lane l -> row l>>2,
  // pos l&3, content chunk (l&3)^((l>>3)&3) of 8 bf16.
  int lr = l >> 2;
  int kc = ((l & 3) ^ ((l >> 3) & 3)) * 8;
  const short* gB0 = wvb + (size_t)(d0 + 32 * w + lr) * H_SZ + kc;
  const short* gB1 = wvb + (size_t)(d0 + 32 * w + 16 + lr) * H_SZ + kc;
  short* lB0 = Bs + (32 * w) * 32;
  short* lB1 = Bs + (32 * w + 16) * 32;

  // fragment-read swizzled positions
  int h7 = l16 & 7;
  int pA0 = ((2 * q) ^ h7) * 4;          // float offset of k-chunk [8q,8q+4)
  int pA1 = ((2 * q + 1) ^ h7) * 4;      // float offset of k-chunk [8q+4,8q+8)
  int posB = (q ^ ((l16 >> 1) & 3)) * 8; // bf16 offset for B frags

  f32x4 acc[4][4];
#pragma unroll
  for (int i = 0; i < 4; ++i)
#pragma unroll
    for (int jj = 0; jj < 4; ++jj) acc[i][jj] = (f32x4){0.f, 0.f, 0.f, 0.f};

  for (int kt = 0; kt <= 32; ++kt) {
    if (kt < 32) {
      int k0 = kt * 32;
#pragma unroll
      for (int s = 0; s < 4; ++s) ldg_lds16(gA[s] + k0, lA[s]);
      ldg_lds16(gB0 + (size_t)k0, lB0);
      ldg_lds16(gB1 + (size_t)k0, lB1);
    } else {
      // location-feature K-step: A = cff (fp32, row stride 32), B = w_loc
#pragma unroll
      for (int s = 0; s < 4; ++s)
        ldg_lds16(cff + (size_t)(row0 + 32 * w + 8 * s + ar) * C_SZ + ac * 4, lA[s]);
      ldg_lds16(wlocb + (size_t)(d0 + 32 * w + lr) * C_SZ + kc, lB0);
      ldg_lds16(wlocb + (size_t)(d0 + 32 * w + 16 + lr) * C_SZ + kc, lB1);
    }
    __syncthreads();

    s16x8 a[4], bb[4];
#pragma unroll
    for (int i = 0; i < 4; ++i) {
      const float* rowp = As + (wm * 64 + i * 16 + l16) * 32;
      f32x4 f0 = *(const f32x4*)(rowp + pA0);
      f32x4 f1 = *(const f32x4*)(rowp + pA1);
      u32x4 pk;
      pk[0] = pack2(f0[0], f0[1]);
      pk[1] = pack2(f0[2], f0[3]);
      pk[2] = pack2(f1[0], f1[1]);
      pk[3] = pack2(f1[2], f1[3]);
      a[i] = *(s16x8*)&pk;
    }
#pragma unroll
    for (int jj = 0; jj < 4; ++jj)
      bb[jj] = *(const s16x8*)(Bs + (wn * 64 + jj * 16 + l16) * 32 + posB);
#pragma unroll
    for (int i = 0; i < 4; ++i)
#pragma unroll
      for (int jj = 0; jj < 4; ++jj)
        acc[i][jj] = __builtin_amdgcn_mfma_f32_16x16x32_bf16(a[i], bb[jj], acc[i][jj], 0, 0, 0);
    __syncthreads();
  }

  // epilogue: e = tanh(acc + qp[d]) (qp includes bias), score += e.w_score
  float qv[4], wv[4];
#pragma unroll
  for (int jj = 0; jj < 4; ++jj) {
    int d = d0 + wn * 64 + jj * 16 + l16;
    qv[jj] = qpb[(size_t)b * DIM_SZ + d];
    wv[jj] = w_score[d];
  }

#pragma unroll
  for (int i = 0; i < 4; ++i) {
#pragma unroll
    for (int r = 0; r < 4; ++r) {
      float part = 0.f;
#pragma unroll
      for (int jj = 0; jj < 4; ++jj)
        part += fast_tanh(acc[i][jj][r] + qv[jj]) * wv[jj];
      part += __shfl_xor(part, 1);
      part += __shfl_xor(part, 2);
      part += __shfl_xor(part, 4);
      part += __shfl_xor(part, 8);
      if (l16 == 0) sred[w][i * 16 + q * 4 + r] = part;
    }
  }
  __syncthreads();
  if (t < 128) {
    int half = t >> 6;
    float v = sred[half * 2][t & 63] + sred[half * 2 + 1][t & 63];
    atomicAdd(&score[row0 + t], v);
  }
}

// ---- fused sigmoid-normalize + context partial; grid (32 b, 8 vc) ----
// per block: recompute full attn row (cheap), then 256-v x 1024-h partial
// context with f32x4 value loads; 4 atomics/thread.
__global__ __launch_bounds__(256) void k_ctx(
    const float* __restrict__ score, const float* __restrict__ b_score,
    const float* __restrict__ value, float* __restrict__ attn_out,
    float* __restrict__ context) {
  __shared__ float als[VLEN_SZ];
  __shared__ float red[4];
  int b = blockIdx.x, vc = blockIdx.y, t = threadIdx.x;
  float bs = b_score[0];
  float sv[8];
  float lsum = 0.f;
  int v0 = t * 8;
#pragma unroll
  for (int k = 0; k < 8; ++k) {
    float ps = score[(size_t)b * VLEN_SZ + v0 + k] + bs;
    float s = 1.0f / (1.0f + __expf(-ps));
    sv[k] = s;
    lsum += s;
    als[v0 + k] = s;
  }
#pragma unroll
  for (int off = 32; off; off >>= 1) lsum += __shfl_xor(lsum, off, 64);
  if ((t & 63) == 0) red[t >> 6] = lsum;
  __syncthreads();
  float inv = 1.0f / (red[0] + red[1] + red[2] + red[3]);
  if (vc == 0) {
#pragma unroll
    for (int k = 0; k < 8; ++k)
      attn_out[(size_t)b * VLEN_SZ + v0 + k] = sv[k] * inv;
  }

  int h0 = t * 4;
  int vbase = vc * 256;
  const float* vp = value + ((size_t)b * VLEN_SZ + vbase) * H_SZ + h0;
  const float* av = als + vbase;
  f32x4 acc = (f32x4){0.f, 0.f, 0.f, 0.f};
#pragma unroll 8
  for (int v = 0; v < 256; ++v) {
    f32x4 xv = *(const f32x4*)(vp + (size_t)v * H_SZ);
    float a = av[v];
    acc[0] += a * xv[0]; acc[1] += a * xv[1];
    acc[2] += a * xv[2]; acc[3] += a * xv[3];
  }
#pragma unroll
  for (int k = 0; k < 4; ++k)
    atomicAdd(&context[(size_t)b * H_SZ + h0 + k], acc[k] * inv);
}

// ---- out[b,h] = b_out[h] + [context|query] . w_out[h,:]; one wave per output ----
__global__ void k_out(const float* __restrict__ context, const float* __restrict__ query,
                      const float* __restrict__ w_out, const float* __restrict__ b_out,
                      float* __restrict__ out) {
  int wid = blockIdx.x * 4 + (threadIdx.x >> 6);
  int lane = threadIdx.x & 63;
  int h = wid >> 5;
  int b = wid & 31;
  const f32x4* w4 = (const f32x4*)(w_out + (size_t)h * 2048);
  const f32x4* c4 = (const f32x4*)(context + (size_t)b * H_SZ);
  const f32x4* q4 = (const f32x4*)(query + (size_t)b * H_SZ);
  float acc = 0.f;
#pragma unroll
  for (int it = 0; it < 8; ++it) {
    int k4 = it * 64 + lane;
    f32x4 w = w4[k4];
    f32x4 c = (k4 < 256) ? c4[k4] : q4[k4 - 256];
    acc += w[0] * c[0] + w[1] * c[1] + w[2] * c[2] + w[3] * c[3];
  }
#pragma unroll
  for (int off = 32; off; off >>= 1) acc += __shfl_xor(acc, off, 64);
  if (lane == 0) out[(size_t)b * H_SZ + h] = acc + b_out[h];
}

extern "C" void kernel_launch(void* const* d_in, const int* in_sizes, int n_in,
                              void* d_out, int out_size, void* d_ws, size_t ws_size,
                              hipStream_t stream) {
  const float* query   = (const float*)d_in[0];
  const float* value   = (const float*)d_in[1];
  const float* prev    = (const float*)d_in[2];
  const float* conv_w  = (const float*)d_in[3];
  const float* conv_b  = (const float*)d_in[4];
  const float* w_loc   = (const float*)d_in[5];
  const float* w_q     = (const float*)d_in[6];
  const float* w_v     = (const float*)d_in[7];
  const float* bias    = (const float*)d_in[8];
  const float* w_score = (const float*)d_in[9];
  const float* b_score = (const float*)d_in[10];
  const float* w_out   = (const float*)d_in[11];
  const float* b_out   = (const float*)d_in[12];

  float* out  = (float*)d_out;                 // (B,1,H) = 32768 floats
  float* attn = out + B_SZ * H_SZ;             // (B,V)   = 65536 floats

  char* ws = (char*)d_ws;
  float* score   = (float*)(ws);               // 256 KB
  float* qpb     = (float*)(ws + (256 << 10)); // 128 KB
  float* context = (float*)(ws + (384 << 10)); // 128 KB
  short* wvb     = (short*)(ws + (512 << 10)); // 2 MB   bf16 w_v
  short* wlocb   = (short*)(ws + (2560 << 10));// 64 KB  bf16 w_loc
  float* cff     = (float*)(ws + (3 << 20));   // 8 MB   fp32 conv features

  k_prep<<<9600, 256, 0, stream>>>(query, w_q, bias, prev, conv_w, conv_b,
                                   w_loc, w_v, qpb, cff, wlocb, wvb, score, context);
  k_score<<<4096, 256, 0, stream>>>(value, wvb, wlocb, cff, qpb, w_score, score);
  k_ctx<<<dim3(B_SZ, 8), 256, 0, stream>>>(score, b_score, value, attn, context);
  k_out<<<(B_SZ * H_SZ) / 4, 256, 0, stream>>>(context, query, w_out, b_out, out);
}